// Round 4
// baseline (113.697 us; speedup 1.0000x reference)
//
#include <hip/hip_runtime.h>

#define NPTS 8192
#define NB 2
#define NPB 128                  // b-points per chunk (staged in LDS per block)
#define NCHUNK (NPTS / NPB)      // 64
#define PPT 8                    // a-points per thread
#define ATILE (256 * PPT)        // 2048 a-points per block

// Init output to +FLT_MAX bits so uint atomicMin == float min (nonneg floats).
__global__ void _chamfer_init(unsigned int* __restrict__ o) {
    o[blockIdx.x * 256 + threadIdx.x] = 0x7F7FFFFFu;
}

// dir = z>>6 (0: a=x,b=y -> dl ; 1: a=y,b=x -> dr), chunk = z&63.
// Block: 2048 a-points (8/thread) x one 128-point b-chunk in LDS.
// Inner: e_j = b2_j - 2 a.b_j  -> 3 FMA + 1 min per pair; 1 broadcast
// ds_read_b128 amortized over 32 VALU insts (8 points).
__global__ __launch_bounds__(256) void _chamfer_min(const float* __restrict__ x,
                                                    const float* __restrict__ y,
                                                    unsigned int* __restrict__ out) {
    const int atile = blockIdx.x;       // 0..3
    const int batch = blockIdx.y;       // 0..1
    const int dir   = blockIdx.z >> 6;  // 0..1
    const int chunk = blockIdx.z & 63;  // 0..63

    const float* a = dir ? y : x;
    const float* b = dir ? x : y;
    unsigned int* o = out + dir * (NB * NPTS) + batch * NPTS;

    __shared__ float4 lds[NPB];

    // Stage: thread t (t<128) pre-transforms b-point t -> (-2bx,-2by,-2bz,|b|^2).
    if (threadIdx.x < NPB) {
        const float* bp = b + batch * NPTS * 3 + (chunk * NPB + (int)threadIdx.x) * 3;
        const float bx = bp[0], by = bp[1], bz = bp[2];
        lds[threadIdx.x] = make_float4(-2.f * bx, -2.f * by, -2.f * bz,
                                       bx * bx + by * by + bz * bz);
    }

    // Each thread owns 8 consecutive a-points: 24 floats = 6 aligned float4.
    const int pbase = atile * ATILE + (int)threadIdx.x * PPT;
    float ax[PPT], ay[PPT], az[PPT], a2[PPT], mn[PPT];
    {
        const float4* asrc = (const float4*)(a + batch * NPTS * 3 + pbase * 3);
        float4 q0 = asrc[0], q1 = asrc[1], q2 = asrc[2];
        float4 q3 = asrc[3], q4 = asrc[4], q5 = asrc[5];
        ax[0]=q0.x; ay[0]=q0.y; az[0]=q0.z;
        ax[1]=q0.w; ay[1]=q1.x; az[1]=q1.y;
        ax[2]=q1.z; ay[2]=q1.w; az[2]=q2.x;
        ax[3]=q2.y; ay[3]=q2.z; az[3]=q2.w;
        ax[4]=q3.x; ay[4]=q3.y; az[4]=q3.z;
        ax[5]=q3.w; ay[5]=q4.x; az[5]=q4.y;
        ax[6]=q4.z; ay[6]=q4.w; az[6]=q5.x;
        ax[7]=q5.y; ay[7]=q5.z; az[7]=q5.w;
    }
    #pragma unroll
    for (int k = 0; k < PPT; ++k) {
        a2[k] = ax[k]*ax[k] + ay[k]*ay[k] + az[k]*az[k];
        mn[k] = 3.4028235e38f;
    }

    __syncthreads();

    #pragma unroll 8
    for (int j = 0; j < NPB; ++j) {
        const float4 bb = lds[j];   // uniform addr -> one broadcast ds_read_b128
        #pragma unroll
        for (int k = 0; k < PPT; ++k) {
            const float e = fmaf(ax[k], bb.x,
                            fmaf(ay[k], bb.y,
                            fmaf(az[k], bb.z, bb.w)));
            mn[k] = fminf(mn[k], e);
        }
    }

    // d = max(a2 + min_e, 0): clamp is monotone, commutes with the chunk-min;
    // result >= 0 so uint bit order == float order for atomicMin.
    #pragma unroll
    for (int k = 0; k < PPT; ++k) {
        const float d = fmaxf(a2[k] + mn[k], 0.f);
        atomicMin(o + pbase + k, __float_as_uint(d));
    }
}

extern "C" void kernel_launch(void* const* d_in, const int* in_sizes, int n_in,
                              void* d_out, int out_size, void* d_ws, size_t ws_size,
                              hipStream_t stream) {
    const float* x = (const float*)d_in[0];
    const float* y = (const float*)d_in[1];
    unsigned int* out = (unsigned int*)d_out;

    _chamfer_init<<<dim3(out_size / 256), dim3(256), 0, stream>>>(out);

    // 4 a-tiles x 2 batches x (2 dirs * 64 chunks) = 1024 blocks -> 4 blocks/CU
    _chamfer_min<<<dim3(4, 2, 128), dim3(256), 0, stream>>>(x, y, out);
}

// Round 5
// 77.898 us; speedup vs baseline: 1.4596x; 1.4596x over previous
//
#include <hip/hip_runtime.h>

#define NPTS 8192
#define NB 2
#define S 8                      // b-chunks per direction
#define BCH (NPTS / S)           // 1024 b-points per chunk
#define SEGP 129                 // padded segment stride in float4 (bank-conflict-free)
#define APB 256                  // a-points per block
#define FMAX 3.4028235e38f

// Phase 1: grid (32, 2, 16): x = a-tile, y = batch, z = dir*8 + chunk.
// Block: 256 a-points x one 1024-point b-chunk in LDS (8 segments of 128,
// padded stride 129 so the 8 concurrent broadcast reads hit disjoint banks).
// Thread (g,s) = (t>>3, t&7): 8 a-points of group g vs b-segment s.
// Partial min over the chunk -> shfl-reduce over s -> plain store to ws.
__global__ __launch_bounds__(256) void _chamfer_part(const float* __restrict__ x,
                                                     const float* __restrict__ y,
                                                     float* __restrict__ ws) {
    const int atile = blockIdx.x;       // 0..31
    const int batch = blockIdx.y;       // 0..1
    const int dir   = blockIdx.z >> 3;  // 0..1
    const int c     = blockIdx.z & 7;   // 0..7

    const float* a = dir ? y : x;
    const float* b = dir ? x : y;

    __shared__ float4 lds[8 * SEGP];

    // Stage b-chunk: thread t transforms 4 points -> (-2bx,-2by,-2bz,|b|^2).
    {
        const float4* bsrc = (const float4*)(b + batch * NPTS * 3 + c * BCH * 3)
                             + (int)threadIdx.x * 3;
        float4 q0 = bsrc[0], q1 = bsrc[1], q2 = bsrc[2];
        float bx[4], by[4], bz[4];
        bx[0]=q0.x; by[0]=q0.y; bz[0]=q0.z;
        bx[1]=q0.w; by[1]=q1.x; bz[1]=q1.y;
        bx[2]=q1.z; by[2]=q1.w; bz[2]=q2.x;
        bx[3]=q2.y; by[3]=q2.z; bz[3]=q2.w;
        #pragma unroll
        for (int i = 0; i < 4; ++i) {
            const int p = (int)threadIdx.x * 4 + i;      // 0..1023
            lds[(p >> 7) * SEGP + (p & 127)] =
                make_float4(-2.f*bx[i], -2.f*by[i], -2.f*bz[i],
                            bx[i]*bx[i] + by[i]*by[i] + bz[i]*bz[i]);
        }
    }

    const int g = (int)threadIdx.x >> 3;  // a-group 0..31 (8 consecutive lanes)
    const int s = (int)threadIdx.x & 7;   // b-segment 0..7
    const int abase = atile * APB + g * 8;

    float ax[8], ay[8], az[8], a2[8], mn[8];
    {
        const float4* asrc = (const float4*)(a + batch * NPTS * 3 + abase * 3);
        float4 q0=asrc[0],q1=asrc[1],q2=asrc[2],q3=asrc[3],q4=asrc[4],q5=asrc[5];
        ax[0]=q0.x; ay[0]=q0.y; az[0]=q0.z;
        ax[1]=q0.w; ay[1]=q1.x; az[1]=q1.y;
        ax[2]=q1.z; ay[2]=q1.w; az[2]=q2.x;
        ax[3]=q2.y; ay[3]=q2.z; az[3]=q2.w;
        ax[4]=q3.x; ay[4]=q3.y; az[4]=q3.z;
        ax[5]=q3.w; ay[5]=q4.x; az[5]=q4.y;
        ax[6]=q4.z; ay[6]=q4.w; az[6]=q5.x;
        ax[7]=q5.y; ay[7]=q5.z; az[7]=q5.w;
    }
    #pragma unroll
    for (int k = 0; k < 8; ++k) {
        a2[k] = ax[k]*ax[k] + ay[k]*ay[k] + az[k]*az[k];
        mn[k] = FMAX;
    }

    __syncthreads();

    // Segment scan: 128 iters, 1 broadcast ds_read_b128 : 32 VALU.
    const float4* seg = &lds[s * SEGP];
    #pragma unroll 8
    for (int j = 0; j < 128; ++j) {
        const float4 bb = seg[j];
        #pragma unroll
        for (int k = 0; k < 8; ++k) {
            const float e = fmaf(ax[k], bb.x,
                            fmaf(ay[k], bb.y,
                            fmaf(az[k], bb.z, bb.w)));
            mn[k] = fminf(mn[k], e);
        }
    }

    // Reduce over the 8 segments: lanes of a group differ only in low 3 bits.
    #pragma unroll
    for (int off = 1; off < 8; off <<= 1) {
        #pragma unroll
        for (int k = 0; k < 8; ++k)
            mn[k] = fminf(mn[k], __shfl_xor(mn[k], off));
    }

    // Lane s==0 stores the chunk-partial: clamp(a2+min) (clamp is monotone,
    // commutes with the later min over chunks). 8 floats = 2 float4 stores.
    if (s == 0) {
        float4 r0 = make_float4(fmaxf(a2[0]+mn[0],0.f), fmaxf(a2[1]+mn[1],0.f),
                                fmaxf(a2[2]+mn[2],0.f), fmaxf(a2[3]+mn[3],0.f));
        float4 r1 = make_float4(fmaxf(a2[4]+mn[4],0.f), fmaxf(a2[5]+mn[5],0.f),
                                fmaxf(a2[6]+mn[6],0.f), fmaxf(a2[7]+mn[7],0.f));
        float4* w = (float4*)(ws + (((dir*NB + batch) * S + c) * NPTS + abase));
        w[0] = r0;
        w[1] = r1;
    }
}

// Phase 2: pure min over the 8 chunk-partials; plain store to d_out.
__global__ __launch_bounds__(256) void _chamfer_reduce(const float* __restrict__ ws,
                                                       float* __restrict__ out) {
    const int w   = blockIdx.x * 256 + (int)threadIdx.x;  // 0..32767
    const int db  = w >> 13;                              // dir*NB+batch 0..3
    const int apt = w & (NPTS - 1);
    const float* p = ws + db * S * NPTS + apt;
    float m = p[0];
    #pragma unroll
    for (int c = 1; c < S; ++c) m = fminf(m, p[c * NPTS]);
    out[w] = m;
}

extern "C" void kernel_launch(void* const* d_in, const int* in_sizes, int n_in,
                              void* d_out, int out_size, void* d_ws, size_t ws_size,
                              hipStream_t stream) {
    const float* x = (const float*)d_in[0];
    const float* y = (const float*)d_in[1];
    float* ws  = (float*)d_ws;   // needs 2*2*8*8192*4 B = 1 MiB
    float* out = (float*)d_out;

    // 32 a-tiles x 2 batches x (2 dirs * 8 chunks) = 1024 blocks
    _chamfer_part<<<dim3(32, 2, 16), dim3(256), 0, stream>>>(x, y, ws);
    _chamfer_reduce<<<dim3(out_size / 256), dim3(256), 0, stream>>>(ws, out);
}